// Round 15
// baseline (547.866 us; speedup 1.0000x reference)
//
#include <hip/hip_runtime.h>
#include <math.h>

#define T_STEPS 8192
#define GROUP   64
#define NQ      (GROUP / 4)          // 16 quads per group
#define NG      (T_STEPS / GROUP)    // 128 groups
#define UH      30

// hardware transcendentals (v_exp_f32 = 2^x, v_log_f32 = log2 x)
__device__ __forceinline__ float hw_exp2(float x) { return __builtin_amdgcn_exp2f(x); }
__device__ __forceinline__ float hw_log2(float x) { return __builtin_amdgcn_logf(x); }

#if __has_builtin(__builtin_amdgcn_fmed3f)
__device__ __forceinline__ float clamp01(float x) { return __builtin_amdgcn_fmed3f(x, 0.0f, 1.0f); }
#else
__device__ __forceinline__ float clamp01(float x) { return fminf(fmaxf(x, 0.0f), 1.0f); }
#endif

// ---------------------------------------------------------------------------
// 4-wave specialized pipeline, GROUP=64. 16 blocks x 256 threads.
//   wave0 (B'): snow + w1 recurrence, forcing from register ping-pong
//               (12xfloat4 chunk prefetch) -> af*perc, af*(qsurf+qif) [lag 0]
//   wave1 (C1): band sums (float4 quad adds)                         [lag 1]
//   wave2 (C2): v2 recurrence -> q into LDS ring                     [lag 2]
//   wave3 (R):  30-tap gamma-UH FIR from ring -> routed (global)     [lag 4]
// R13 post-mortem: per-step cost pinned at ~100cy across all overhead cuts
// => latency-floor suspicion (trans dep latency ~40cy). This round removes
// the LAST overhead candidate: A->B LDS handoff (A merged into B', forcing
// prefetched into registers). Two-sided prediction: 300-325us if overhead,
// 335-345us if floor. >=330 => declare structural floor.
// ---------------------------------------------------------------------------
__global__ __launch_bounds__(256, 1) void fuse_pipe_kernel(
    const float* __restrict__ raw,        // [64][29]
    const float* __restrict__ forcing,    // [8192][3]
    const float* __restrict__ state_init, // [2]
    const float* __restrict__ area_frac,  // [16]
    const float* __restrict__ mean_elev,  // [16]
    float* __restrict__ routed)           // d_out: [64][8192]
{
    const int tid  = threadIdx.x;
    const int wid  = tid >> 6;      // 0..3
    const int lane = tid & 63;
    const int grp  = lane >> 4;     // ensemble within wave
    const int nb   = lane & 15;     // band
    const int e    = blockIdx.x * 4 + grp;

    // B' -> C1: row padded to 67 float4
    __shared__ float4 bufP4[2][NQ][67];   // af*perc
    __shared__ float4 bufQ4[2][NQ][67];   // af*(qsurf+qif)
    // C1 -> C2: per-(e, quad) sums
    __shared__ float4 bufR4[2][4][NQ + 1];   // rech sums
    __shared__ float4 bufS4[2][4][NQ + 1];   // surface-q sums
    // C2 -> R: q ring, 4 slots x 64 steps per ensemble (row padded to 257)
    __shared__ float qring[4][257];
    // total ~77 KB

    // zero-init ring (R's negative-time taps at g=0 read zeros)
    for (int k = tid; k < 4 * 257; k += 256)
        ((float*)qring)[k] = 0.0f;

    const float* rp = raw + e * 29;
    auto phys = [&](int idx, float lo, float hi) {
        float x = rp[idx];
        float s = 1.0f / (1.0f + expf(-x));
        return lo + (hi - lo) * s;
    };
    const float s1max = phys(0,  50.0f,  5000.0f);
    const float s2max = phys(1,  100.0f, 10000.0f);
    const float ku    = phys(6,  0.01f,  1000.0f);
    const float c_exp = phys(7,  1.0f,   20.0f);
    const float ki    = phys(11, 0.01f,  1000.0f);
    const float ks    = phys(12, 0.001f, 10000.0f);
    const float n_exp = phys(13, 1.0f,   10.0f);
    const float acmax = phys(17, 0.05f,  0.95f);
    const float b_exp = phys(18, 0.001f, 3.0f);
    const float train = phys(22, -2.0f,  4.0f);
    const float tmelt = phys(23, -2.0f,  4.0f);
    const float mrate = phys(24, 1.0f,   10.0f);
    const float lapse = phys(25, -9.8f,  0.0f);
    const float opg   = phys(26, 0.0f,   1.0f);

    const float delev  = (mean_elev[nb] - 1500.0f) / 1000.0f;
    const float tshift = lapse * delev;
    const float pmult  = fmaxf(1.0f + opg * delev, 0.0f);
    const float af     = area_frac[nb];
    const float inv_s1max = 1.0f / s1max;
    const float inv_s2max = 1.0f / s2max;
    const float kup    = ku * inv_s1max;
    const float ksn    = ks * inv_s2max;
    const float afku   = af * ku;
    const float afki   = af * ki;
    const float afs1   = af * s1max;

    float swe = 0.0f;
    float w1  = state_init[0] * inv_s1max;   // <= 1 always
    float v2  = state_init[1] * inv_s2max;   // may exceed 1 (g==0 handles)

    // gamma-UH weights for wave R (static tap indices -> registers)
    float wloc[UH];
    if (wid == 3) {
        const float x     = raw[e * 29 + 21];            // mu_t raw
        const float sig   = 1.0f / (1.0f + expf(-x));
        const float delay = 0.01f + (5.0f - 0.01f) * sig;
        const float lgd   = logf(delay);
        const float invd  = 1.0f / delay;
        float s = 0.0f;
        #pragma unroll
        for (int l = 0; l < UH; ++l) {
            const float tm = (float)l + 0.5f;
            const float lp = 1.5f * logf(tm) - tm * invd
                           - 0.28468287047291918f - 2.5f * lgd;
            wloc[l] = expf(lp);
            s += wloc[l];
        }
        const float inv = 1.0f / s;
        #pragma unroll
        for (int l = 0; l < UH; ++l) wloc[l] *= inv;
    }

    float* __restrict__ out = routed + (size_t)e * T_STEPS;
    const float4* __restrict__ fvec = (const float4*)forcing;  // 48 float4/group

    // B' forcing ping-pong: chunk = 12 float4 = 16 steps
    float4 fb[2][12];
    if (wid == 0) {
        #pragma unroll
        for (int j = 0; j < 12; ++j) fb[0][j] = fvec[j];   // group 0, chunk 0
    }

    for (int i = 0; i < NG + 4; ++i) {
        if (wid == 0) {
            // ---- stage B': snow + w1 recurrence, group i ----
            if (i < NG) {
                const int pb_ = i & 1;
                #pragma unroll
                for (int h = 0; h < 4; ++h) {              // 4 chunks x 16 steps
                    const int cur = h & 1, nxt = cur ^ 1;
                    // issue next-chunk loads (clamped at tail)
                    {
                        int nh = h + 1, ng = i;
                        if (nh == 4) { nh = 0; ng = (i + 1 < NG) ? i + 1 : NG - 1; }
                        const float4* s4 = fvec + (ng * 48 + nh * 12);
                        #pragma unroll
                        for (int j = 0; j < 12; ++j) fb[nxt][j] = s4[j];
                    }
                    // compute 16 steps from fb[cur]
                    float4 oP, oQ;
                    #pragma unroll
                    for (int s = 0; s < 16; ++s) {
                        const float p    = (&fb[cur][(3*s    ) >> 2].x)[(3*s    ) & 3];
                        const float pet  = (&fb[cur][(3*s + 1) >> 2].x)[(3*s + 1) & 3];
                        const float tair = (&fb[cur][(3*s + 2) >> 2].x)[(3*s + 2) & 3];
                        // snow bucket (feed-forward swe recurrence)
                        const float tb   = tair + tshift;
                        const float pcp  = p * pmult;
                        const float snow = (tb > train) ? 0.0f : pcp;
                        const float ssn  = swe + snow;
                        const float mcap = mrate * fmaxf(tb - tmelt, 0.0f);
                        const float swen = fmaxf(ssn - mcap, 0.0f);
                        const float infl = pcp + swe - swen;     // rain + melt
                        swe = swen;
                        const float fi  = infl * inv_s1max;
                        const float fcv = fmaf(-(pet + ki), inv_s1max, 1.0f);
                        const float fap = acmax * fi;               // off-chain
                        // chain: log -> mul -> exp -> fma -> fma -> med3
                        const float lg  = hw_log2(w1);              // log2(0)=-inf ok
                        const float pwc = hw_exp2(c_exp * lg);      // w1^c
                        const float pwb = hw_exp2(b_exp * lg);      // w1^b
                        const float u   = fmaf(fcv, w1, fi);        // parallel arm
                        const float u1  = fmaf(-kup, pwc, u);
                        const float u2  = fmaf(-fap, pwb, u1);
                        const float over1 = fmaxf(u2 - 1.0f, 0.0f); // off-chain
                        const float qift  = afki * w1;              // off-chain
                        w1 = clamp01(u2);
                        const float qsxn = fap * pwb;
                        const int tt = h * 16 + s, c3 = tt & 3;
                        (&oP.x)[c3] = afku * pwc;                   // af*perc
                        (&oQ.x)[c3] = fmaf(afs1, qsxn + over1, qift);
                        if (c3 == 3) {
                            bufP4[pb_][tt >> 2][lane] = oP;
                            bufQ4[pb_][tt >> 2][lane] = oQ;
                        }
                    }
                    // pin the prefetched chunk AFTER compute (overlap window)
                    #pragma unroll
                    for (int j = 0; j < 12; ++j)
                        asm volatile("" : "+v"(fb[nxt][j].x), "+v"(fb[nxt][j].y),
                                          "+v"(fb[nxt][j].z), "+v"(fb[nxt][j].w));
                }
            }
        } else if (wid == 1) {
            // ---- stage C1: band sums (float4 quad-step adds), group i-1 ----
            const int g = i - 1;
            if (g >= 0 && g < NG) {
                const int pb_ = g & 1;
                const int arr = lane >> 5;        // 0: P(rech), 1: Q(surface)
                const int se  = (lane >> 3) & 3;  // ensemble
                const int tq  = lane & 7;         // quad-step base
                #pragma unroll
                for (int j = 0; j < 2; ++j) {
                    const int q_ = tq + 8 * j;
                    const float4* src = arr ? &bufQ4[pb_][q_][se * 16]
                                            : &bufP4[pb_][q_][se * 16];
                    float4 s = src[0];
                    #pragma unroll
                    for (int n = 1; n < 16; ++n) {
                        const float4 v = src[n];
                        s.x += v.x; s.y += v.y; s.z += v.z; s.w += v.w;
                    }
                    if (arr) bufS4[pb_][se][q_] = s;
                    else     bufR4[pb_][se][q_] = s;
                }
            }
        } else if (wid == 2) {
            // ---- stage C2: v2 recurrence, group i-2 -> q into ring ----
            const int g = i - 2;
            if (g >= 0 && g < NG) {
                const int pb_ = g & 1;
                const int slot = (g & 3) * 64;
                float qk0 = 0.0f, qk1 = 0.0f, qk2 = 0.0f, qk3 = 0.0f;
                auto c2body = [&](bool clampPw) {
                    #pragma unroll
                    for (int k = 0; k < NQ; ++k) {
                        const float4 r4 = bufR4[pb_][grp][k];   // broadcast
                        const float4 s4 = bufS4[pb_][grp][k];
                        #pragma unroll
                        for (int c3 = 0; c3 < 4; ++c3) {
                            const int tt = 4 * k + c3;
                            const float rech = (&r4.x)[c3];
                            const float qsum = (&s4.x)[c3];
                            // chain: log -> mul(+min) -> exp -> fma -> med3
                            const float lg2 = hw_log2(v2);
                            float m = n_exp * lg2;
                            if (clampPw) m = fminf(m, 0.0f);
                            const float pwm = hw_exp2(m);     // clip(w2)^n
                            const float u   = fmaf(rech, inv_s2max, v2);
                            const float u2  = fmaf(-ksn, pwm, u);
                            const float over2 = fmaxf(u2 - 1.0f, 0.0f);
                            v2 = clamp01(u2);
                            const float q = fmaf(s2max, over2, fmaf(ks, pwm, qsum));
                            const bool sel = (tt & 15) == nb;
                            if      (tt < 16) qk0 = sel ? q : qk0;
                            else if (tt < 32) qk1 = sel ? q : qk1;
                            else if (tt < 48) qk2 = sel ? q : qk2;
                            else              qk3 = sel ? q : qk3;
                        }
                    }
                };
                if (g == 0) c2body(true); else c2body(false);

                qring[grp][slot + nb]      = qk0;
                qring[grp][slot + nb + 16] = qk1;
                qring[grp][slot + nb + 32] = qk2;
                qring[grp][slot + nb + 48] = qk3;
            }
        } else {
            // ---- stage R: gamma-UH FIR, group i-4 -> routed (global) ----
            const int g = i - 4;
            if (g >= 0 && g < NG) {
                const int base = (g & 3) * 64;
                #pragma unroll
                for (int j = 0; j < 4; ++j) {
                    const int pl = nb + 16 * j;           // 0..63
                    float acc = 0.0f;
                    #pragma unroll
                    for (int l = 0; l < UH; ++l) {
                        const int idx = (base + pl - l) & 255;
                        acc = fmaf(wloc[l], qring[grp][idx], acc);
                    }
                    out[g * GROUP + pl] = acc;
                }
            }
        }
        __syncthreads();
    }
}

// ---------------------------------------------------------------------------
extern "C" void kernel_launch(void* const* d_in, const int* in_sizes, int n_in,
                              void* d_out, int out_size, void* d_ws, size_t ws_size,
                              hipStream_t stream) {
    const float* raw        = (const float*)d_in[0];   // (64, 29)
    const float* forcing    = (const float*)d_in[1];   // (8192, 3)
    const float* state_init = (const float*)d_in[2];   // (2,)
    const float* area_frac  = (const float*)d_in[3];   // (16,)
    const float* mean_elev  = (const float*)d_in[4];   // (16,)

    float* out = (float*)d_out;                        // (64, 8192) routed

    fuse_pipe_kernel<<<16, 256, 0, stream>>>(raw, forcing, state_init,
                                             area_frac, mean_elev, out);
}

// Round 16
// 339.888 us; speedup vs baseline: 1.6119x; 1.6119x over previous
//
#include <hip/hip_runtime.h>
#include <math.h>

#define T_STEPS 8192
#define GROUP   64
#define NQ      (GROUP / 4)          // 16 quads per group
#define NG      (T_STEPS / GROUP)    // 128 groups
#define UH      30

// hardware transcendentals (v_exp_f32 = 2^x, v_log_f32 = log2 x)
__device__ __forceinline__ float hw_exp2(float x) { return __builtin_amdgcn_exp2f(x); }
__device__ __forceinline__ float hw_log2(float x) { return __builtin_amdgcn_logf(x); }

#if __has_builtin(__builtin_amdgcn_fmed3f)
__device__ __forceinline__ float clamp01(float x) { return __builtin_amdgcn_fmed3f(x, 0.0f, 1.0f); }
#else
__device__ __forceinline__ float clamp01(float x) { return fminf(fmaxf(x, 0.0f), 1.0f); }
#endif

// ---------------------------------------------------------------------------
// 5-wave specialized pipeline, GROUP=64. 16 blocks x 320 threads.
//   wave0 (A):  snow bucket -> infl/s1max, 1-(pet+ki)/s1max      [lag 0]
//   wave1 (B):  w1 recurrence -> af*perc, af*(qsurf+qif)         [lag 1]
//   wave2 (C1): band sums (float4 quad adds)                     [lag 2]
//   wave3 (C2): v2 recurrence -> q into LDS ring                 [lag 3]
//   wave4 (R):  30-tap gamma-UH FIR from ring -> routed (global) [lag 5]
// This is the R13 structure (best measured: 340us total), reverted after
// R14's A-into-B merge regression proved the A->B handoff was free (hidden
// in B's chain-stall slack). B and C2 sit at ~95% of their dependent-chain
// floors (2 serial transcendentals x ~40cy + ~16cy VALU = ~96cy/step).
// ---------------------------------------------------------------------------
__global__ __launch_bounds__(320, 1) void fuse_pipe_kernel(
    const float* __restrict__ raw,        // [64][29]
    const float* __restrict__ forcing,    // [8192][3]
    const float* __restrict__ state_init, // [2]
    const float* __restrict__ area_frac,  // [16]
    const float* __restrict__ mean_elev,  // [16]
    float* __restrict__ routed)           // d_out: [64][8192]
{
    const int tid  = threadIdx.x;
    const int wid  = tid >> 6;      // 0..4
    const int lane = tid & 63;
    const int grp  = lane >> 4;     // ensemble within wave
    const int nb   = lane & 15;     // band
    const int e    = blockIdx.x * 4 + grp;

    // A -> B: packed 4 steps per float4, [quad][lane]
    __shared__ float4 bufI4[2][NQ][64];   // infl * inv_s1max
    __shared__ float4 bufC4[2][NQ][64];   // 1 - (pet+ki)*inv_s1max
    // B -> C1: row padded to 67 float4
    __shared__ float4 bufP4[2][NQ][67];   // af*perc
    __shared__ float4 bufQ4[2][NQ][67];   // af*(qsurf+qif)
    // C1 -> C2: per-(e, quad) sums
    __shared__ float4 bufR4[2][4][NQ + 1];   // rech sums
    __shared__ float4 bufS4[2][4][NQ + 1];   // surface-q sums
    // C2 -> R: q ring, 4 slots x 64 steps per ensemble (row padded to 257)
    __shared__ float qring[4][257];

    // zero-init ring (R's negative-time taps at g=0 read slot 3 = zeros)
    for (int k = tid; k < 4 * 257; k += 320)
        ((float*)qring)[k] = 0.0f;

    const float* rp = raw + e * 29;
    auto phys = [&](int idx, float lo, float hi) {
        float x = rp[idx];
        float s = 1.0f / (1.0f + expf(-x));
        return lo + (hi - lo) * s;
    };
    const float s1max = phys(0,  50.0f,  5000.0f);
    const float s2max = phys(1,  100.0f, 10000.0f);
    const float ku    = phys(6,  0.01f,  1000.0f);
    const float c_exp = phys(7,  1.0f,   20.0f);
    const float ki    = phys(11, 0.01f,  1000.0f);
    const float ks    = phys(12, 0.001f, 10000.0f);
    const float n_exp = phys(13, 1.0f,   10.0f);
    const float acmax = phys(17, 0.05f,  0.95f);
    const float b_exp = phys(18, 0.001f, 3.0f);
    const float train = phys(22, -2.0f,  4.0f);
    const float tmelt = phys(23, -2.0f,  4.0f);
    const float mrate = phys(24, 1.0f,   10.0f);
    const float lapse = phys(25, -9.8f,  0.0f);
    const float opg   = phys(26, 0.0f,   1.0f);

    const float delev  = (mean_elev[nb] - 1500.0f) / 1000.0f;
    const float tshift = lapse * delev;
    const float pmult  = fmaxf(1.0f + opg * delev, 0.0f);
    const float af     = area_frac[nb];
    const float inv_s1max = 1.0f / s1max;
    const float inv_s2max = 1.0f / s2max;
    const float kup    = ku * inv_s1max;
    const float ksn    = ks * inv_s2max;
    const float afku   = af * ku;
    const float afki   = af * ki;
    const float afs1   = af * s1max;

    float swe = 0.0f;
    float w1  = state_init[0] * inv_s1max;   // <= 1 always
    float v2  = state_init[1] * inv_s2max;   // may exceed 1 (g==0 handles)

    // gamma-UH weights for wave R (static tap indices -> registers)
    float wloc[UH];
    if (wid == 4) {
        const float x     = raw[e * 29 + 21];            // mu_t raw
        const float sig   = 1.0f / (1.0f + expf(-x));
        const float delay = 0.01f + (5.0f - 0.01f) * sig;
        const float lgd   = logf(delay);
        const float invd  = 1.0f / delay;
        float s = 0.0f;
        #pragma unroll
        for (int l = 0; l < UH; ++l) {
            const float tm = (float)l + 0.5f;
            const float lp = 1.5f * logf(tm) - tm * invd
                           - 0.28468287047291918f - 2.5f * lgd;
            wloc[l] = expf(lp);
            s += wloc[l];
        }
        const float inv = 1.0f / s;
        #pragma unroll
        for (int l = 0; l < UH; ++l) wloc[l] *= inv;
    }

    float* __restrict__ out = routed + (size_t)e * T_STEPS;
    const float4* __restrict__ fvec = (const float4*)forcing;  // 48 float4/group

    for (int i = 0; i < NG + 5; ++i) {
        if (wid == 0) {
            // ---- stage A: snow bucket + normalized precompute, group i ----
            if (i < NG) {
                const int pb_ = i & 1;
                const int base = i * 48;
                #pragma unroll
                for (int h = 0; h < 4; ++h) {          // 4 chunks x 16 steps
                    float f[48];
                    #pragma unroll
                    for (int j = 0; j < 12; ++j) {
                        const float4 L = fvec[base + h * 12 + j];
                        f[4*j+0] = L.x; f[4*j+1] = L.y; f[4*j+2] = L.z; f[4*j+3] = L.w;
                    }
                    float4 vi, vc;
                    #pragma unroll
                    for (int s = 0; s < 16; ++s) {
                        const int tt = h * 16 + s;
                        const float p    = f[3*s + 0];
                        const float pet  = f[3*s + 1];
                        const float tair = f[3*s + 2];
                        const float tb   = tair + tshift;
                        const float pcp  = p * pmult;
                        const float snow = (tb > train) ? 0.0f : pcp;
                        const float ssn  = swe + snow;
                        const float mcap = mrate * fmaxf(tb - tmelt, 0.0f);
                        const float swen = fmaxf(ssn - mcap, 0.0f);
                        const float infl = pcp + swe - swen;    // rain + melt
                        swe = swen;
                        const int c3 = tt & 3;
                        (&vi.x)[c3] = infl * inv_s1max;
                        (&vc.x)[c3] = fmaf(-(pet + ki), inv_s1max, 1.0f);
                        if (c3 == 3) {
                            bufI4[pb_][tt >> 2][lane] = vi;
                            bufC4[pb_][tt >> 2][lane] = vc;
                        }
                    }
                }
            }
        } else if (wid == 1) {
            // ---- stage B: w1 recurrence, group i-1 (hoisted reads, no pins) ----
            const int g = i - 1;
            if (g >= 0 && g < NG) {
                const int pb_ = g & 1;
                float4 fi4[NQ], fc4[NQ];
                #pragma unroll
                for (int k = 0; k < NQ; ++k) {
                    fi4[k] = bufI4[pb_][k][lane];
                    fc4[k] = bufC4[pb_][k][lane];
                }
                #pragma unroll
                for (int k = 0; k < NQ; ++k) {
                    float4 oP, oQ;
                    #pragma unroll
                    for (int c3 = 0; c3 < 4; ++c3) {
                        const float fi  = (&fi4[k].x)[c3];
                        const float fcv = (&fc4[k].x)[c3];
                        const float fap = acmax * fi;               // off-chain
                        // chain: log -> mul -> exp -> fma -> fma -> med3
                        const float lg  = hw_log2(w1);              // log2(0)=-inf ok
                        const float pwc = hw_exp2(c_exp * lg);      // w1^c
                        const float pwb = hw_exp2(b_exp * lg);      // w1^b
                        const float u   = fmaf(fcv, w1, fi);        // parallel arm
                        const float u1  = fmaf(-kup, pwc, u);
                        const float u2  = fmaf(-fap, pwb, u1);
                        const float over1 = fmaxf(u2 - 1.0f, 0.0f); // off-chain
                        const float qift  = afki * w1;              // off-chain
                        w1 = clamp01(u2);
                        const float qsxn = fap * pwb;
                        (&oP.x)[c3] = afku * pwc;                   // af*perc
                        (&oQ.x)[c3] = fmaf(afs1, qsxn + over1, qift);
                    }
                    bufP4[pb_][k][lane] = oP;
                    bufQ4[pb_][k][lane] = oQ;
                }
            }
        } else if (wid == 2) {
            // ---- stage C1: band sums (float4 quad-step adds), group i-2 ----
            const int g = i - 2;
            if (g >= 0 && g < NG) {
                const int pb_ = g & 1;
                const int arr = lane >> 5;        // 0: P(rech), 1: Q(surface)
                const int se  = (lane >> 3) & 3;  // ensemble
                const int tq  = lane & 7;         // quad-step base
                #pragma unroll
                for (int j = 0; j < 2; ++j) {
                    const int q_ = tq + 8 * j;
                    const float4* src = arr ? &bufQ4[pb_][q_][se * 16]
                                            : &bufP4[pb_][q_][se * 16];
                    float4 s = src[0];
                    #pragma unroll
                    for (int n = 1; n < 16; ++n) {
                        const float4 v = src[n];
                        s.x += v.x; s.y += v.y; s.z += v.z; s.w += v.w;
                    }
                    if (arr) bufS4[pb_][se][q_] = s;
                    else     bufR4[pb_][se][q_] = s;
                }
            }
        } else if (wid == 3) {
            // ---- stage C2: v2 recurrence, group i-3 -> q into ring ----
            const int g = i - 3;
            if (g >= 0 && g < NG) {
                const int pb_ = g & 1;
                const int slot = (g & 3) * 64;
                float qk0 = 0.0f, qk1 = 0.0f, qk2 = 0.0f, qk3 = 0.0f;
                auto c2body = [&](bool clampPw) {
                    #pragma unroll
                    for (int k = 0; k < NQ; ++k) {
                        const float4 r4 = bufR4[pb_][grp][k];   // broadcast
                        const float4 s4 = bufS4[pb_][grp][k];
                        #pragma unroll
                        for (int c3 = 0; c3 < 4; ++c3) {
                            const int tt = 4 * k + c3;
                            const float rech = (&r4.x)[c3];
                            const float qsum = (&s4.x)[c3];
                            // chain: log -> mul(+min) -> exp -> fma -> med3
                            const float lg2 = hw_log2(v2);
                            float m = n_exp * lg2;
                            if (clampPw) m = fminf(m, 0.0f);
                            const float pwm = hw_exp2(m);     // clip(w2)^n
                            const float u   = fmaf(rech, inv_s2max, v2);
                            const float u2  = fmaf(-ksn, pwm, u);
                            const float over2 = fmaxf(u2 - 1.0f, 0.0f);
                            v2 = clamp01(u2);
                            const float q = fmaf(s2max, over2, fmaf(ks, pwm, qsum));
                            const bool sel = (tt & 15) == nb;
                            if      (tt < 16) qk0 = sel ? q : qk0;
                            else if (tt < 32) qk1 = sel ? q : qk1;
                            else if (tt < 48) qk2 = sel ? q : qk2;
                            else              qk3 = sel ? q : qk3;
                        }
                    }
                };
                if (g == 0) c2body(true); else c2body(false);

                qring[grp][slot + nb]      = qk0;
                qring[grp][slot + nb + 16] = qk1;
                qring[grp][slot + nb + 32] = qk2;
                qring[grp][slot + nb + 48] = qk3;
            }
        } else {
            // ---- stage R: gamma-UH FIR, group i-5 -> routed (global) ----
            const int g = i - 5;
            if (g >= 0 && g < NG) {
                const int base = (g & 3) * 64;
                #pragma unroll
                for (int j = 0; j < 4; ++j) {
                    const int pl = nb + 16 * j;           // 0..63
                    float acc = 0.0f;
                    #pragma unroll
                    for (int l = 0; l < UH; ++l) {
                        const int idx = (base + pl - l) & 255;
                        acc = fmaf(wloc[l], qring[grp][idx], acc);
                    }
                    out[g * GROUP + pl] = acc;
                }
            }
        }
        __syncthreads();
    }
}

// ---------------------------------------------------------------------------
extern "C" void kernel_launch(void* const* d_in, const int* in_sizes, int n_in,
                              void* d_out, int out_size, void* d_ws, size_t ws_size,
                              hipStream_t stream) {
    const float* raw        = (const float*)d_in[0];   // (64, 29)
    const float* forcing    = (const float*)d_in[1];   // (8192, 3)
    const float* state_init = (const float*)d_in[2];   // (2,)
    const float* area_frac  = (const float*)d_in[3];   // (16,)
    const float* mean_elev  = (const float*)d_in[4];   // (16,)

    float* out = (float*)d_out;                        // (64, 8192) routed

    fuse_pipe_kernel<<<16, 320, 0, stream>>>(raw, forcing, state_init,
                                             area_frac, mean_elev, out);
}